// Round 1
// baseline (133.510 us; speedup 1.0000x reference)
//
#include <hip/hip_runtime.h>
#include <hip/hip_bf16.h>

typedef __attribute__((ext_vector_type(8))) short bf16x8;
typedef __attribute__((ext_vector_type(4))) float f32x4;
typedef __attribute__((ext_vector_type(4))) float float4_t;

constexpr int Lseq = 2048;
constexpr int Hh   = 16;
constexpr int Dd   = 64;
constexpr int ROWS = Hh * Dd;   // 1024 floats between consecutive l for fixed (n,h)
constexpr int KB   = 64;        // kv tile
constexpr int QB   = 64;        // q tile per block (16 per wave)
constexpr int LDP  = 72;        // padded LDS leading dim (shorts)

// (1/sqrt(64)) * log2(e): fold scale + exp2-domain conversion into Q
constexpr float SCALE_LOG2E = 0.18033688011112042f;

__device__ __forceinline__ short f2bf(float f) {
  unsigned u = __builtin_bit_cast(unsigned, f);
  u += 0x7fffu + ((u >> 16) & 1u);   // RNE (inputs finite)
  return (short)(u >> 16);
}

__device__ __forceinline__ bf16x8 pack8(float4_t a, float4_t b) {
  bf16x8 r;
  r[0] = f2bf(a[0]); r[1] = f2bf(a[1]); r[2] = f2bf(a[2]); r[3] = f2bf(a[3]);
  r[4] = f2bf(b[0]); r[5] = f2bf(b[1]); r[6] = f2bf(b[2]); r[7] = f2bf(b[3]);
  return r;
}

__global__ __launch_bounds__(256, 4)
void attn_fwd(const float* __restrict__ Qg, const float* __restrict__ Kg,
              const float* __restrict__ Vg, float* __restrict__ Og) {
  __shared__ short k_lds[KB][LDP];        // K tile, row-major [k][d]
  __shared__ short v_lds[Dd][LDP];        // V tile, TRANSPOSED [d][k]
  __shared__ short p_lds[4][16][LDP];     // per-wave P tile [q][k]

  // XCD-aware bijective swizzle: nwg=1024, 128 consecutive per XCD
  int wg  = blockIdx.x;
  int swz = (wg & 7) * 128 + (wg >> 3);
  int nh  = swz >> 5;          // 0..31  (n*16 + h)
  int qt  = swz & 31;          // q tile 0..31
  const size_t base = (size_t)(nh >> 4) * Lseq * ROWS + (size_t)(nh & 15) * Dd;

  const int tid  = threadIdx.x;
  const int lane = tid & 63;
  const int wid  = tid >> 6;   // wave 0..3
  const int lq   = lane & 15;  // within-16 index
  const int hg   = lane >> 4;  // 16-lane group 0..3

  // ---- Q fragments (A-layout: row = lane&15, k = (lane>>4)*8 + j), scaled ----
  bf16x8 qf[2];
  {
    const float* qrow = Qg + base + (size_t)(qt * QB + wid * 16 + lq) * ROWS + hg * 8;
#pragma unroll
    for (int kk = 0; kk < 2; ++kk) {
      float4_t a = *(const float4_t*)(qrow + kk * 32);
      float4_t b = *(const float4_t*)(qrow + kk * 32 + 4);
#pragma unroll
      for (int j = 0; j < 4; ++j) { a[j] *= SCALE_LOG2E; b[j] *= SCALE_LOG2E; }
      qf[kk] = pack8(a, b);
    }
  }

  f32x4 acc[4] = {};            // O accumulator: col d = nt*16+lq, row q = hg*4+reg
  float mrow[4], lrow[4];
#pragma unroll
  for (int r = 0; r < 4; ++r) { mrow[r] = -1e30f; lrow[r] = 0.f; }

  for (int kt = 0; kt < Lseq; kt += KB) {
    __syncthreads();   // all waves done reading previous tile

    // ---- stage K tile: 4 threads per row, 16 floats each ----
    {
      int r  = tid >> 2;
      int c0 = (tid & 3) * 16;
      const float* src = Kg + base + (size_t)(kt + r) * ROWS + c0;
      float4_t a = ((const float4_t*)src)[0];
      float4_t b = ((const float4_t*)src)[1];
      float4_t c = ((const float4_t*)src)[2];
      float4_t d = ((const float4_t*)src)[3];
      *(bf16x8*)&k_lds[r][c0]     = pack8(a, b);
      *(bf16x8*)&k_lds[r][c0 + 8] = pack8(c, d);
    }
    // ---- stage V tile transposed: lane = d, wave covers 8 k-rows per pass ----
#pragma unroll
    for (int p = 0; p < 2; ++p) {
      int kr = p * 32 + wid * 8;
      const float* src = Vg + base + (size_t)(kt + kr) * ROWS + lane;
      bf16x8 w;
#pragma unroll
      for (int j = 0; j < 8; ++j) w[j] = f2bf(src[(size_t)j * ROWS]);
      *(bf16x8*)&v_lds[lane][kr] = w;
    }
    __syncthreads();

    // ---- S = Q K^T (already in exp2 domain) ----
    f32x4 s[4] = {};
#pragma unroll
    for (int nt = 0; nt < 4; ++nt)
#pragma unroll
      for (int kk = 0; kk < 2; ++kk) {
        bf16x8 kb = *(const bf16x8*)&k_lds[nt * 16 + lq][hg * 8 + kk * 32];
        s[nt] = __builtin_amdgcn_mfma_f32_16x16x32_bf16(qf[kk], kb, s[nt], 0, 0, 0);
      }

    // ---- online softmax (row q = hg*4+reg; row spread over 16 lanes of group) ----
#pragma unroll
    for (int r = 0; r < 4; ++r) {
      float v0 = fmaxf(fmaxf(s[0][r], s[1][r]), fmaxf(s[2][r], s[3][r]));
#pragma unroll
      for (int m = 1; m <= 8; m <<= 1) v0 = fmaxf(v0, __shfl_xor(v0, m));
      float mnew = fmaxf(mrow[r], v0);
      float scl  = __builtin_amdgcn_exp2f(mrow[r] - mnew);
      mrow[r] = mnew;
      float rs = 0.f;
#pragma unroll
      for (int nt = 0; nt < 4; ++nt) {
        float p = __builtin_amdgcn_exp2f(s[nt][r] - mnew);
        s[nt][r] = p;
        rs += p;
      }
#pragma unroll
      for (int m = 1; m <= 8; m <<= 1) rs += __shfl_xor(rs, m);
      lrow[r] = lrow[r] * scl + rs;
#pragma unroll
      for (int nt = 0; nt < 4; ++nt) acc[nt][r] *= scl;
    }

    // ---- P: C-layout -> A-layout via per-wave LDS round trip ----
#pragma unroll
    for (int nt = 0; nt < 4; ++nt)
#pragma unroll
      for (int r = 0; r < 4; ++r)
        p_lds[wid][hg * 4 + r][nt * 16 + lq] = f2bf(s[nt][r]);

    asm volatile("s_waitcnt lgkmcnt(0)" ::: "memory");

    // ---- O += P V ----
#pragma unroll
    for (int kk = 0; kk < 2; ++kk) {
      bf16x8 pa = *(const bf16x8*)&p_lds[wid][lq][hg * 8 + kk * 32];
#pragma unroll
      for (int nt = 0; nt < 4; ++nt) {
        bf16x8 vb = *(const bf16x8*)&v_lds[nt * 16 + lq][hg * 8 + kk * 32];
        acc[nt] = __builtin_amdgcn_mfma_f32_16x16x32_bf16(pa, vb, acc[nt], 0, 0, 0);
      }
    }
  }

  // ---- epilogue: divide by row sum, store fp32 ----
#pragma unroll
  for (int r = 0; r < 4; ++r) {
    float inv = 1.0f / lrow[r];
    float* orow = Og + base + (size_t)(qt * QB + wid * 16 + hg * 4 + r) * ROWS;
#pragma unroll
    for (int nt = 0; nt < 4; ++nt)
      orow[nt * 16 + lq] = acc[nt][r] * inv;
  }
}

extern "C" void kernel_launch(void* const* d_in, const int* in_sizes, int n_in,
                              void* d_out, int out_size, void* d_ws, size_t ws_size,
                              hipStream_t stream) {
  const float* Q = (const float*)d_in[0];
  const float* K = (const float*)d_in[1];
  const float* V = (const float*)d_in[2];
  float* O = (float*)d_out;
  attn_fwd<<<dim3(1024), dim3(256), 0, stream>>>(Q, K, V, O);
}

// Round 2
// 69.943 us; speedup vs baseline: 1.9088x; 1.9088x over previous
//
#include <hip/hip_runtime.h>
#include <hip/hip_bf16.h>

typedef __attribute__((ext_vector_type(8))) short bf16x8;
typedef __attribute__((ext_vector_type(4))) float float4_t;
typedef __attribute__((ext_vector_type(16))) float f32x16;
typedef __attribute__((ext_vector_type(4))) int int4v;
typedef __attribute__((ext_vector_type(2))) int int2v;

constexpr int Lseq = 2048;
constexpr int Dd   = 64;
constexpr int ROWS = 1024;   // H*D floats between consecutive l for fixed (n,h)
constexpr int KB   = 64;     // kv tile rows
constexpr float SCALE_LOG2E = 0.18033688011112042f;  // (1/sqrt(64))*log2(e)
constexpr float THR = 8.0f;  // defer-max threshold (exp2 domain)

__device__ __forceinline__ short f2bf(float f) {
  unsigned u = __builtin_bit_cast(unsigned, f);
  u += 0x7fffu + ((u >> 16) & 1u);   // RNE, inputs finite
  return (short)(u >> 16);
}

__device__ __forceinline__ bf16x8 pack8(float4_t a, float4_t b) {
  bf16x8 r;
  r[0] = f2bf(a[0]); r[1] = f2bf(a[1]); r[2] = f2bf(a[2]); r[3] = f2bf(a[3]);
  r[4] = f2bf(b[0]); r[5] = f2bf(b[1]); r[6] = f2bf(b[2]); r[7] = f2bf(b[3]);
  return r;
}

__device__ __forceinline__ int cvtpk(float lo, float hi) {
  int r;
  asm("v_cvt_pk_bf16_f32 %0, %1, %2" : "=v"(r) : "v"(lo), "v"(hi));
  return r;
}

// v_permlane32_swap_b32: a becomes [a_lo, b_lo], b becomes [a_hi, b_hi]
__device__ __forceinline__ void plswap(int& a, int& b) {
  int2v r = __builtin_amdgcn_permlane32_swap(a, b, false, false);
  a = r[0]; b = r[1];
}

#define MFMA32(A, B, C) __builtin_amdgcn_mfma_f32_32x32x16_bf16((A), (B), (C), 0, 0, 0)

__global__ __launch_bounds__(256, 2)
void attn_fwd(const float* __restrict__ Qg, const float* __restrict__ Kg,
              const float* __restrict__ Vg, float* __restrict__ Og) {
  // [buf][0]=K row-major [64 k][64 d], [buf][1]=V transposed [64 d][64 k], XOR-swizzled
  __shared__ __align__(16) short kv_lds[2][2][KB * Dd];   // 32 KiB

  // XCD-bijective swizzle: nwg=512, 64 consecutive per XCD (16 blocks share a slice)
  int wg  = blockIdx.x;
  int swz = (wg & 7) * 64 + (wg >> 3);
  int nh  = swz >> 4;          // 0..31 = n*16+h
  int qt  = swz & 15;          // q tile 0..15 (128 q rows each)
  const size_t base = (size_t)(nh >> 4) * Lseq * ROWS + (size_t)(nh & 15) * Dd;

  const int tid  = threadIdx.x;
  const int lane = tid & 63;
  const int wid  = tid >> 6;   // wave 0..3, owns q rows qt*128 + wid*32 ..+32
  const int lq   = lane & 31;
  const int hi   = lane >> 5;

  // ---- Q B-fragments: lane holds Q[q=lq][d = c*16 + hi*8 + j], scaled ----
  bf16x8 qf[4];
  {
    const float* qrow = Qg + base + (size_t)(qt * 128 + wid * 32 + lq) * ROWS + hi * 8;
#pragma unroll
    for (int c = 0; c < 4; ++c) {
      float4_t a = *(const float4_t*)(qrow + c * 16);
      float4_t b = *(const float4_t*)(qrow + c * 16 + 4);
#pragma unroll
      for (int j = 0; j < 4; ++j) { a[j] *= SCALE_LOG2E; b[j] *= SCALE_LOG2E; }
      qf[c] = pack8(a, b);
    }
  }

  // ---- staging assignments ----
  const float* ksrc = Kg + base + (size_t)(tid >> 2) * ROWS + (tid & 3) * 16;
  const float* vsrc = Vg + base + (size_t)((tid >> 6) * 8) * ROWS + (tid & 63);
  // K write: row tid>>2, two 16B at cols (tid&3)*16(+8)
  const int krow = tid >> 2;
  const int kwb  = krow * 128 + (tid & 3) * 32;
  const int kswz = (krow & 7) << 4;
  const int kb0  = kwb ^ kswz, kb1 = (kwb + 16) ^ kswz;
  // V^T write: row d=tid&63, octs tid>>6 and +4
  const int vd   = tid & 63;
  const int vwb  = vd * 128 + (tid >> 6) * 16;
  const int vswz = (vd & 7) << 4;
  const int vb0  = vwb ^ vswz, vb1 = (vwb + 64) ^ vswz;
  // fragment read offsets: row = t2*32+lq, byte = row*128 + c*32 + hi*16 (^ swz)
  const int rsw = (lq & 7) << 4;
  const int rb0 = lq * 128 + hi * 16;
  const int rb1 = (32 + lq) * 128 + hi * 16;

  float4_t kr[4]; float vr[16];
  auto stage_issue = [&](int kt) {
    const float* kp = ksrc + (size_t)kt * ROWS;
#pragma unroll
    for (int i = 0; i < 4; ++i) kr[i] = *(const float4_t*)(kp + i * 4);
    const float* vp = vsrc + (size_t)kt * ROWS;
#pragma unroll
    for (int j = 0; j < 8; ++j) vr[j] = vp[(size_t)j * ROWS];
#pragma unroll
    for (int j = 0; j < 8; ++j) vr[8 + j] = vp[(size_t)(32 + j) * ROWS];
  };
  auto stage_write = [&](int buf) {
    char* kdst = (char*)&kv_lds[buf][0][0];
    *(bf16x8*)(kdst + kb0) = pack8(kr[0], kr[1]);
    *(bf16x8*)(kdst + kb1) = pack8(kr[2], kr[3]);
    char* vdst = (char*)&kv_lds[buf][1][0];
    bf16x8 w0, w1;
#pragma unroll
    for (int j = 0; j < 8; ++j) { w0[j] = f2bf(vr[j]); w1[j] = f2bf(vr[8 + j]); }
    *(bf16x8*)(vdst + vb0) = w0;
    *(bf16x8*)(vdst + vb1) = w1;
  };

  float m = 0.f, l = 0.f;
  f32x16 acc0, acc1;
#pragma unroll
  for (int r = 0; r < 16; ++r) { acc0[r] = 0.f; acc1[r] = 0.f; }

  stage_issue(0);
  stage_write(0);
  __syncthreads();

  int cur = 0;
  for (int kt = 0; kt < Lseq; kt += KB) {
    const bool more = (kt + KB) < Lseq;
    if (more) stage_issue(kt + KB);

    // ---- S^T = K·Q (C init = -m folds running max into MFMA) ----
    f32x16 s0, s1;
#pragma unroll
    for (int r = 0; r < 16; ++r) { s0[r] = -m; s1[r] = -m; }
    const char* kld = (const char*)&kv_lds[cur][0][0];
#pragma unroll
    for (int c = 0; c < 4; ++c) {
      bf16x8 ka = *(const bf16x8*)(kld + ((rb0 + c * 32) ^ rsw));
      s0 = MFMA32(ka, qf[c], s0);
    }
#pragma unroll
    for (int c = 0; c < 4; ++c) {
      bf16x8 ka = *(const bf16x8*)(kld + ((rb1 + c * 32) ^ rsw));
      s1 = MFMA32(ka, qf[c], s1);
    }

    // ---- row max (relative to m), in-register + one permlane swap ----
    float pm = s0[0];
#pragma unroll
    for (int r = 1; r < 16; ++r) pm = fmaxf(pm, s0[r]);
#pragma unroll
    for (int r = 0; r < 16; ++r) pm = fmaxf(pm, s1[r]);
    {
      int a = __float_as_int(pm), b = a;
      plswap(a, b);
      pm = fmaxf(__int_as_float(a), __int_as_float(b));
    }

    // ---- defer-max: rescale only when max grew past THR ----
    float dm = 0.f;
    if (!__all(pm <= THR)) {
      float mn = fmaxf(pm, 0.f);
      dm = mn;
      m += mn;
      float f = __builtin_amdgcn_exp2f(-mn);
      l *= f;
#pragma unroll
      for (int r = 0; r < 16; ++r) {
        int qr = (r & 3) + 8 * (r >> 2) + 4 * hi;
        float fq = __shfl(f, qr);
        acc0[r] *= fq; acc1[r] *= fq;
      }
    }

    // ---- P = exp2(S - m) ----
#pragma unroll
    for (int r = 0; r < 16; ++r) {
      s0[r] = __builtin_amdgcn_exp2f(s0[r] - dm);
      s1[r] = __builtin_amdgcn_exp2f(s1[r] - dm);
    }

    // ---- row sum ----
    float rs = 0.f;
#pragma unroll
    for (int r = 0; r < 16; ++r) rs += s0[r] + s1[r];
    {
      int a = __float_as_int(rs), b = a;
      plswap(a, b);
      rs = __int_as_float(a) + __int_as_float(b);
    }
    l += rs;

    // ---- P → bf16 A-frags: 16 cvt_pk + 8 permlane32_swap (T12) ----
    bf16x8 pa[4];
#pragma unroll
    for (int c = 0; c < 4; ++c) {
      const f32x16& sv = (c < 2) ? s0 : s1;
      const int br = (c & 1) * 8;
      int w0 = cvtpk(sv[br + 0], sv[br + 1]);
      int w1 = cvtpk(sv[br + 2], sv[br + 3]);
      int w2 = cvtpk(sv[br + 4], sv[br + 5]);
      int w3 = cvtpk(sv[br + 6], sv[br + 7]);
      plswap(w0, w2);
      plswap(w1, w3);
      int4v t; t[0] = w0; t[1] = w1; t[2] = w2; t[3] = w3;
      pa[c] = __builtin_bit_cast(bf16x8, t);
    }

    // ---- O += P·V ----
    const char* vld = (const char*)&kv_lds[cur][1][0];
#pragma unroll
    for (int c = 0; c < 4; ++c) {
      bf16x8 vb = *(const bf16x8*)(vld + ((rb0 + c * 32) ^ rsw));
      acc0 = MFMA32(pa[c], vb, acc0);
    }
#pragma unroll
    for (int c = 0; c < 4; ++c) {
      bf16x8 vb = *(const bf16x8*)(vld + ((rb1 + c * 32) ^ rsw));
      acc1 = MFMA32(pa[c], vb, acc1);
    }

    // ---- late LDS write of next tile (loads already in flight) ----
    if (more) stage_write(cur ^ 1);
    __syncthreads();
    cur ^= 1;
  }

  // ---- epilogue: normalize, store ----
  float linv = 1.0f / l;
#pragma unroll
  for (int r = 0; r < 16; ++r) {
    int qr = (r & 3) + 8 * (r >> 2) + 4 * hi;
    float li = __shfl(linv, qr);
    float* orow = Og + base + (size_t)(qt * 128 + wid * 32 + qr) * ROWS;
    orow[lq]      = acc0[r] * li;
    orow[32 + lq] = acc1[r] * li;
  }
}

extern "C" void kernel_launch(void* const* d_in, const int* in_sizes, int n_in,
                              void* d_out, int out_size, void* d_ws, size_t ws_size,
                              hipStream_t stream) {
  const float* Q = (const float*)d_in[0];
  const float* K = (const float*)d_in[1];
  const float* V = (const float*)d_in[2];
  float* O = (float*)d_out;
  attn_fwd<<<dim3(512), dim3(256), 0, stream>>>(Q, K, V, O);
}

// Round 3
// 65.789 us; speedup vs baseline: 2.0294x; 1.0632x over previous
//
#include <hip/hip_runtime.h>
#include <hip/hip_bf16.h>

typedef __attribute__((ext_vector_type(8))) short bf16x8;
typedef __attribute__((ext_vector_type(4))) float float4_t;
typedef __attribute__((ext_vector_type(2))) float f32x2;
typedef __attribute__((ext_vector_type(16))) float f32x16;
typedef __attribute__((ext_vector_type(4))) int int4v;
typedef __attribute__((ext_vector_type(2))) int int2v;
typedef __attribute__((ext_vector_type(4))) unsigned uint4v;

constexpr int Lseq = 2048;
constexpr int ROWS = 1024;   // H*D floats between consecutive l for fixed (n,h)
constexpr int KB   = 64;
constexpr float SCALE_LOG2E = 0.18033688011112042f;  // (1/sqrt(64))*log2(e)
constexpr float THR = 8.0f;

__device__ __forceinline__ int cvtpk(float lo, float hi) {
  int r; asm("v_cvt_pk_bf16_f32 %0, %1, %2" : "=v"(r) : "v"(lo), "v"(hi)); return r;
}
__device__ __forceinline__ f32x2 pkadd(f32x2 a, f32x2 b) {
  f32x2 r; asm("v_pk_add_f32 %0, %1, %2" : "=v"(r) : "v"(a), "v"(b)); return r;
}
__device__ __forceinline__ void plswap(int& a, int& b) {
  int2v r = __builtin_amdgcn_permlane32_swap(a, b, false, false);
  a = r[0]; b = r[1];
}
__device__ __forceinline__ float mx3(float a, float b, float c) {
  return fmaxf(fmaxf(a, b), c);
}
__device__ __forceinline__ int4v pk8(float4_t a, float4_t b) {
  int4v t;
  t[0] = cvtpk(a[0], a[1]); t[1] = cvtpk(a[2], a[3]);
  t[2] = cvtpk(b[0], b[1]); t[3] = cvtpk(b[2], b[3]);
  return t;
}
__device__ __forceinline__ uint4v make_srsrc(const void* p) {
  unsigned long long a = (unsigned long long)p;
  uint4v r; r[0] = (unsigned)a; r[1] = (unsigned)(a >> 32) & 0xffffu;
  r[2] = 0xffffffffu; r[3] = 0x00020000u;
  return r;
}
__device__ __forceinline__ float blds(unsigned voff, uint4v rs, int soff) {
  float d;
  asm volatile("buffer_load_dword %0, %1, %2, %3 offen"
               : "=v"(d) : "v"(voff), "s"(rs), "s"(soff));
  return d;
}

#define MFMA32(A, B, C) __builtin_amdgcn_mfma_f32_32x32x16_bf16((A), (B), (C), 0, 0, 0)

__global__ __launch_bounds__(256, 2)
void attn_fwd(const float* __restrict__ Qg, const float* __restrict__ Kg,
              const float* __restrict__ Vg, float* __restrict__ Og) {
  // [buf][0]=K row-major [64 k][64 d], [buf][1]=V transposed [64 d][64 k], XOR-swizzled
  __shared__ __align__(16) short kv_lds[2][2][KB * 64];   // 32 KiB

  int wg  = blockIdx.x;
  int swz = (wg & 7) * 64 + (wg >> 3);       // XCD-bijective, nwg=512
  int nh  = swz >> 4;
  int qt  = swz & 15;
  const size_t base = (size_t)(nh >> 4) * Lseq * ROWS + (size_t)(nh & 15) * 64;

  const int tid  = threadIdx.x;
  const int lane = tid & 63;
  const int wid  = tid >> 6;
  const int lq   = lane & 31;
  const int hi   = lane >> 5;

  // ---- Q B-fragments: lane holds Q[q=lq][d = c*16 + hi*8 + j], scaled ----
  bf16x8 qf[4];
  {
    const float* qrow = Qg + base + (size_t)(qt * 128 + wid * 32 + lq) * ROWS + hi * 8;
#pragma unroll
    for (int c = 0; c < 4; ++c) {
      float4_t a = *(const float4_t*)(qrow + c * 16);
      float4_t b = *(const float4_t*)(qrow + c * 16 + 4);
#pragma unroll
      for (int j = 0; j < 4; ++j) { a[j] *= SCALE_LOG2E; b[j] *= SCALE_LOG2E; }
      qf[c] = __builtin_bit_cast(bf16x8, pk8(a, b));
    }
  }

  // ---- staging: SRSRC descriptors + 32-bit voffsets ----
  const uint4v rsK = make_srsrc(Kg + base);
  const uint4v rsV = make_srsrc(Vg + base);
  unsigned voffk  = (unsigned)(((tid >> 2) * ROWS + (tid & 3) * 16) * 4);
  unsigned voffv  = (unsigned)((((tid >> 6) * 8) * ROWS + (tid & 63)) * 4);
  unsigned voffv2 = voffv + 131072u;   // +32 rows

  // K write: row tid>>2, two 16B at cols (tid&3)*16(+8)
  const int krow = tid >> 2;
  const int kwb  = krow * 128 + (tid & 3) * 32;
  const int kswz = (krow & 7) << 4;
  const int kb0  = kwb ^ kswz, kb1 = (kwb + 16) ^ kswz;
  // V^T write: row d=tid&63, slots tid>>6 and +4
  const int vd   = tid & 63;
  const int vwb  = vd * 128 + (tid >> 6) * 16;
  const int vswz = (vd & 7) << 4;
  const int vb0  = vwb ^ vswz, vb1 = (vwb + 64) ^ vswz;
  // fragment reads: byte = row*128 + c*32 + hi*16 (^ swz)
  const int rsw = (lq & 7) << 4;
  const int rb0 = lq * 128 + hi * 16;
  const int rb1 = (32 + lq) * 128 + hi * 16;

  float4_t kr[4]; float vr[16];
  auto stage_issue = [&]() {
    asm volatile(
        "buffer_load_dwordx4 %0, %4, %5, 0 offen\n\t"
        "buffer_load_dwordx4 %1, %4, %5, 0 offen offset:16\n\t"
        "buffer_load_dwordx4 %2, %4, %5, 0 offen offset:32\n\t"
        "buffer_load_dwordx4 %3, %4, %5, 0 offen offset:48"
        : "=v"(kr[0]), "=v"(kr[1]), "=v"(kr[2]), "=v"(kr[3])
        : "v"(voffk), "s"(rsK));
#pragma unroll
    for (int j = 0; j < 8; ++j) {
      vr[j]     = blds(voffv,  rsV, j * 4096);
      vr[8 + j] = blds(voffv2, rsV, j * 4096);
    }
    voffk += 262144u; voffv += 262144u; voffv2 += 262144u;
  };
  auto stage_write = [&](int buf) {
    asm volatile("s_waitcnt vmcnt(0)"
                 : "+v"(kr[0]), "+v"(kr[1]), "+v"(kr[2]), "+v"(kr[3]),
                   "+v"(vr[0]), "+v"(vr[1]), "+v"(vr[2]), "+v"(vr[3]),
                   "+v"(vr[4]), "+v"(vr[5]), "+v"(vr[6]), "+v"(vr[7]),
                   "+v"(vr[8]), "+v"(vr[9]), "+v"(vr[10]), "+v"(vr[11]),
                   "+v"(vr[12]), "+v"(vr[13]), "+v"(vr[14]), "+v"(vr[15]));
    char* kdst = (char*)&kv_lds[buf][0][0];
    *(int4v*)(kdst + kb0) = pk8(kr[0], kr[1]);
    *(int4v*)(kdst + kb1) = pk8(kr[2], kr[3]);
    char* vdst = (char*)&kv_lds[buf][1][0];
    int4v w0, w1;
    w0[0] = cvtpk(vr[0], vr[1]);   w0[1] = cvtpk(vr[2], vr[3]);
    w0[2] = cvtpk(vr[4], vr[5]);   w0[3] = cvtpk(vr[6], vr[7]);
    w1[0] = cvtpk(vr[8], vr[9]);   w1[1] = cvtpk(vr[10], vr[11]);
    w1[2] = cvtpk(vr[12], vr[13]); w1[3] = cvtpk(vr[14], vr[15]);
    *(int4v*)(vdst + vb0) = w0;
    *(int4v*)(vdst + vb1) = w1;
  };

  float m = 0.f, l = 0.f;
  f32x16 acc0, acc1;
#pragma unroll
  for (int r = 0; r < 16; ++r) { acc0[r] = 0.f; acc1[r] = 0.f; }

  stage_issue();
  stage_write(0);
  __syncthreads();

  int cur = 0;
  for (int kt = 0; kt < Lseq; kt += KB) {
    const bool more = (kt + KB) < Lseq;
    if (more) stage_issue();

    // ---- S^T = K·Q (C init = -m folds running max into MFMA) ----
    f32x16 s0, s1;
#pragma unroll
    for (int r = 0; r < 16; ++r) { s0[r] = -m; s1[r] = -m; }
    const char* kld = (const char*)&kv_lds[cur][0][0];
#pragma unroll
    for (int c = 0; c < 4; ++c) {
      bf16x8 ka = *(const bf16x8*)(kld + ((rb0 + c * 32) ^ rsw));
      s0 = MFMA32(ka, qf[c], s0);
    }
#pragma unroll
    for (int c = 0; c < 4; ++c) {
      bf16x8 ka = *(const bf16x8*)(kld + ((rb1 + c * 32) ^ rsw));
      s1 = MFMA32(ka, qf[c], s1);
    }

    // ---- row max via max3 triples + one permlane swap ----
    float w0 = mx3(s0[0], s0[1], s0[2]);
    float w1 = mx3(s0[3], s0[4], s0[5]);
    float w2 = mx3(s0[6], s0[7], s0[8]);
    float w3 = mx3(s0[9], s0[10], s0[11]);
    float w4 = mx3(s0[12], s0[13], s0[14]);
    float w5 = mx3(s0[15], s1[0], s1[1]);
    float w6 = mx3(s1[2], s1[3], s1[4]);
    float w7 = mx3(s1[5], s1[6], s1[7]);
    float w8 = mx3(s1[8], s1[9], s1[10]);
    float w9 = mx3(s1[11], s1[12], s1[13]);
    float wa = fmaxf(s1[14], s1[15]);
    float x0 = mx3(w0, w1, w2);
    float x1 = mx3(w3, w4, w5);
    float x2 = mx3(w6, w7, w8);
    float x3 = mx3(w9, wa, x2);
    float pm = mx3(x0, x1, x3);
    {
      int a = __float_as_int(pm), b = a;
      plswap(a, b);
      pm = fmaxf(__int_as_float(a), __int_as_float(b));
    }

    // ---- defer-max: fast path has no subtract ----
    if (__all(pm <= THR)) {
#pragma unroll
      for (int r = 0; r < 16; ++r) {
        s0[r] = __builtin_amdgcn_exp2f(s0[r]);
        s1[r] = __builtin_amdgcn_exp2f(s1[r]);
      }
    } else {
      float mn = fmaxf(pm, 0.f);
      m += mn;
      float f = __builtin_amdgcn_exp2f(-mn);
      l *= f;
#pragma unroll
      for (int r = 0; r < 16; ++r) {
        int qr = (r & 3) + 8 * (r >> 2) + 4 * hi;
        float fq = __shfl(f, qr);
        acc0[r] *= fq; acc1[r] *= fq;
      }
#pragma unroll
      for (int r = 0; r < 16; ++r) {
        s0[r] = __builtin_amdgcn_exp2f(s0[r] - mn);
        s1[r] = __builtin_amdgcn_exp2f(s1[r] - mn);
      }
    }

    // ---- row sum via v_pk_add_f32 tree ----
#define S2(v, i) (f32x2{(v)[2 * (i)], (v)[2 * (i) + 1]})
    {
      f32x2 u0 = pkadd(S2(s0, 0), S2(s0, 1));
      f32x2 u1 = pkadd(S2(s0, 2), S2(s0, 3));
      f32x2 u2 = pkadd(S2(s0, 4), S2(s0, 5));
      f32x2 u3 = pkadd(S2(s0, 6), S2(s0, 7));
      f32x2 u4 = pkadd(S2(s1, 0), S2(s1, 1));
      f32x2 u5 = pkadd(S2(s1, 2), S2(s1, 3));
      f32x2 u6 = pkadd(S2(s1, 4), S2(s1, 5));
      f32x2 u7 = pkadd(S2(s1, 6), S2(s1, 7));
      u0 = pkadd(u0, u1); u2 = pkadd(u2, u3);
      u4 = pkadd(u4, u5); u6 = pkadd(u6, u7);
      u0 = pkadd(u0, u2); u4 = pkadd(u4, u6);
      u0 = pkadd(u0, u4);
      float rs = u0[0] + u0[1];
      int a = __float_as_int(rs), b = a;
      plswap(a, b);
      l += __int_as_float(a) + __int_as_float(b);
    }
#undef S2

    // ---- P → bf16 A-frags: 16 cvt_pk + 8 permlane32_swap ----
    bf16x8 pa[4];
#pragma unroll
    for (int c = 0; c < 4; ++c) {
      const f32x16& sv = (c < 2) ? s0 : s1;
      const int br = (c & 1) * 8;
      int t0 = cvtpk(sv[br + 0], sv[br + 1]);
      int t1 = cvtpk(sv[br + 2], sv[br + 3]);
      int t2 = cvtpk(sv[br + 4], sv[br + 5]);
      int t3 = cvtpk(sv[br + 6], sv[br + 7]);
      plswap(t0, t2);
      plswap(t1, t3);
      int4v t; t[0] = t0; t[1] = t1; t[2] = t2; t[3] = t3;
      pa[c] = __builtin_bit_cast(bf16x8, t);
    }

    // ---- O += P·V ----
    const char* vld = (const char*)&kv_lds[cur][1][0];
#pragma unroll
    for (int c = 0; c < 4; ++c) {
      bf16x8 vb = *(const bf16x8*)(vld + ((rb0 + c * 32) ^ rsw));
      acc0 = MFMA32(pa[c], vb, acc0);
    }
#pragma unroll
    for (int c = 0; c < 4; ++c) {
      bf16x8 vb = *(const bf16x8*)(vld + ((rb1 + c * 32) ^ rsw));
      acc1 = MFMA32(pa[c], vb, acc1);
    }

    if (more) stage_write(cur ^ 1);
    __syncthreads();
    cur ^= 1;
  }

  // ---- epilogue ----
  float linv = 1.0f / l;
#pragma unroll
  for (int r = 0; r < 16; ++r) {
    int qr = (r & 3) + 8 * (r >> 2) + 4 * hi;
    float li = __shfl(linv, qr);
    float* orow = Og + base + (size_t)(qt * 128 + wid * 32 + qr) * ROWS;
    orow[lq]      = acc0[r] * li;
    orow[32 + lq] = acc1[r] * li;
  }
}

extern "C" void kernel_launch(void* const* d_in, const int* in_sizes, int n_in,
                              void* d_out, int out_size, void* d_ws, size_t ws_size,
                              hipStream_t stream) {
  const float* Q = (const float*)d_in[0];
  const float* K = (const float*)d_in[1];
  const float* V = (const float*)d_in[2];
  float* O = (float*)d_out;
  attn_fwd<<<dim3(512), dim3(256), 0, stream>>>(Q, K, V, O);
}